// Round 15
// baseline (144.923 us; speedup 1.0000x reference)
//
#include <hip/hip_runtime.h>
#include <stdint.h>

#define D_DIM 512
#define NSTEPS 10
#define ALPHA0 0.1f
#define DT_C 0.1f
#define BETA_C 2.8982753492378875f

typedef __attribute__((ext_vector_type(8))) short short8;
typedef __attribute__((ext_vector_type(4))) float floatx4;
typedef __attribute__((ext_vector_type(4))) unsigned short ushortx4;

__device__ __forceinline__ unsigned short f32_to_bf16(float f) {
    union { float f; uint32_t u; } v;
    v.f = f;
    uint32_t u = v.u;
    return (unsigned short)((u + 0x7FFFu + ((u >> 16) & 1u)) >> 16);
}

// ---------------------------------------------------------------------------
// Kernel 1: build L_rw and store PRE-TILED in MFMA fragment order (round 13,
// passed). Tile (eg32, kk) stored as two 1KB halves; byte l*16 of a half is
// exactly the fragment MFMA-lane l consumes.
// ---------------------------------------------------------------------------
__global__ __launch_bounds__(64) void prep_kernel(
    const float* __restrict__ W,
    unsigned short* __restrict__ Ltl)    // 512 KiB, tiled layout
{
    const int e = blockIdx.x;
    const int lane = threadIdx.x;
    const float* w = W + (size_t)e * D_DIM + lane * 8;
    const float4 v0 = *(const float4*)w;
    const float4 v1 = *(const float4*)(w + 4);
    float a[8] = { fabsf(v0.x), fabsf(v0.y), fabsf(v0.z), fabsf(v0.w),
                   fabsf(v1.x), fabsf(v1.y), fabsf(v1.z), fabsf(v1.w) };
    float s = a[0] + a[1] + a[2] + a[3] + a[4] + a[5] + a[6] + a[7];
#pragma unroll
    for (int off = 1; off < 64; off <<= 1) s += __shfl_xor(s, off, 64);
    const float inv = 1.0f / fmaxf(s, 1e-8f);
    short8 pk;
#pragma unroll
    for (int j = 0; j < 8; ++j) {
        const float diag = ((lane * 8 + j) == e) ? 1.0f : 0.0f;
        pk[j] = (short)f32_to_bf16(diag - a[j] * inv);
    }
    const int eg = e >> 5, half = (e >> 4) & 1, r = e & 15;
    const int kk = lane >> 2, qp = lane & 3;
    char* dst = (char*)Ltl + ((size_t)(eg * 32 + kk * 2 + half) << 10)
                + ((size_t)(qp * 16 + r) << 4);
    *(short8*)dst = pk;
}

// ---------------------------------------------------------------------------
// Kernel 2: full 10-step settle, ONE launch, 32 blocks x 256 thr (4 waves).
// ROUND-15 RESTRUCTURE: the 16-wave version was LDS-pipe-bound (L round-trip
// through LDS = 1.28 MB/step/CU ~= 5.3us/step). With the TILED Ltl layout each
// fragment is a contiguous 1KB burst, so L goes L2 -> VGPR directly:
//   wave w owns e-rows [128w, 128w+128) = 8 m-frags; per kk it loads 8 frags
//   (8KB in flight/wave, 32KB/CU -> saturates the ~60 B/cy/CU L2 return path)
//   and issues 8 MFMAs. No DMA, no Lt staging, no vmcnt choreography.
// 4-wave block -> 256-VGPR cap (the 64-reg/16-wave spill trap of rounds 5-10
// does not apply): census At/Bt 64 + acc 32 + a[8] 64 + addr ~= 210 < 256.
// Abuf (A bf16 [c][e] swizzled, 16 KB) single-buffered, plain __syncthreads.
// Epilogue: Gtl = g*A10 + (1-g)I PRE-TILED (fragment order), eg16 = wave*8+m.
// ---------------------------------------------------------------------------
__global__ __launch_bounds__(256) void chain_kernel(
    const unsigned short* __restrict__ Ltl,   // tiled L (see prep)
    const float* __restrict__ prec,
    const float* __restrict__ gate_alpha,
    unsigned short* __restrict__ Gtl)         // tiled G, diag folded
{
    const int tid = threadIdx.x;
    const int wave = tid >> 6, lane = tid & 63;
    const int lrow = lane & 15, q = lane >> 4;
    const int c_glob = blockIdx.x * 16 + lrow;
    const int ebase = wave * 128;

    __shared__ unsigned short Abuf[16 * D_DIM];    // 16 KiB, swizzled [c][e]
    char* abuf = (char*)Abuf;

    floatx4 At[8], Bt[8];
#pragma unroll
    for (int m = 0; m < 8; ++m) {
#pragma unroll
        for (int j = 0; j < 4; ++j) {
            const int e = ebase + m * 16 + q * 4 + j;
            At[m][j] = (e == c_glob) ? 1.0f : 0.0f;
            Bt[m][j] = 0.0f;
        }
    }

    // init Abuf with A0 = I
#pragma unroll
    for (int m = 0; m < 8; ++m) {
        ushortx4 pk;
#pragma unroll
        for (int j = 0; j < 4; ++j) pk[j] = f32_to_bf16(At[m][j]);
        int byte = lrow * 1024 + (ebase + m * 16 + q * 4) * 2;
        byte ^= (lrow & 7) << 4;
        *(ushortx4*)(abuf + byte) = pk;
    }
    __syncthreads();

    // lane's L-frag base: frag (m,kk) at lb + (m>>1)*32768 + (kk*2+(m&1))*1024
    const char* lb = (const char*)Ltl + ((size_t)wave << 17) + (size_t)lane * 16;

    for (int step = 0; step < NSTEPS; ++step) {
        floatx4 acc[8] = {};
#pragma unroll
        for (int kk = 0; kk < 16; ++kk) {
            short8 a[8];
#pragma unroll
            for (int m = 0; m < 8; ++m)
                a[m] = *(const short8*)(lb + ((m >> 1) << 15) + ((kk * 2 + (m & 1)) << 10));
            int bbyte = lrow * 1024 + kk * 64 + q * 16;
            bbyte ^= (lrow & 7) << 4;
            const short8 b = *(const short8*)(abuf + bbyte);
#pragma unroll
            for (int m = 0; m < 8; ++m)
                acc[m] = __builtin_amdgcn_mfma_f32_16x16x32_bf16(a[m], b, acc[m], 0, 0, 0);
        }

        // state update; prec reloaded per step (short live range, L1-hit)
#pragma unroll
        for (int m = 0; m < 8; ++m) {
            const float4 pm = *(const float4*)(prec + ebase + m * 16 + q * 4);
            const float pa[4] = { pm.x, pm.y, pm.z, pm.w };
#pragma unroll
            for (int j = 0; j < 4; ++j) {
                const int e = ebase + m * 16 + q * 4 + j;
                const float p = pa[j];
                const float tgt = (e == c_glob) ? p : 0.0f;
                const float force = -acc[m][j] - (ALPHA0 + p) * At[m][j]
                                    + tgt - BETA_C * Bt[m][j];
                Bt[m][j] += DT_C * force;
                At[m][j] += DT_C * Bt[m][j];
            }
        }

        if (step < NSTEPS - 1) {
            __syncthreads();
#pragma unroll
            for (int m = 0; m < 8; ++m) {
                ushortx4 pk;
#pragma unroll
                for (int j = 0; j < 4; ++j) pk[j] = f32_to_bf16(At[m][j]);
                int byte = lrow * 1024 + (ebase + m * 16 + q * 4) * 2;
                byte ^= (lrow & 7) << 4;
                *(ushortx4*)(abuf + byte) = pk;
            }
            __syncthreads();
        }
    }

    // epilogue: G = g*A10 + (1-g)I, written PRE-TILED (fragment order).
    // E = ebase+m*16+q*4+j -> eg16 = wave*8+m; D = c_glob, kt = c_glob>>5.
    const float g = tanhf(gate_alpha[0]);
    const int kt = c_glob >> 5;
    const int lq = ((c_glob >> 3) & 3) * 16;
    const int jb = (c_glob & 7) * 2;
#pragma unroll
    for (int m = 0; m < 8; ++m) {
        char* tbase = (char*)Gtl + ((size_t)((wave * 8 + m) * 16 + kt) << 10);
#pragma unroll
        for (int j = 0; j < 4; ++j) {
            const int e = ebase + m * 16 + q * 4 + j;
            float val = g * At[m][j];
            if (e == c_glob) val += (1.0f - g);
            *(unsigned short*)(tbase + (q * 4 + j + lq) * 16 + jb) = f32_to_bf16(val);
        }
    }
}

// ---------------------------------------------------------------------------
// Kernel 3: out = Hbf @ G^T (diag folded into G).
// ROUND-15: 64-row tiles, 256 blocks x 256 thr (4 waves). Halves the G
// re-read (round 14: 512 blocks x 512 KB = 256 MB of L2/L3 traffic -> the
// hidden wall). Each wave computes all 64 rows x its 128 cols:
//   acc[4][8] (128 VGPR) + a[4] + b[4] (n split in two halves) ~= 210 regs,
//   cap 256 (no __launch_bounds__ floor), LDS 64 KB -> 2 blocks/CU.
// G consumed directly from L2/L3 in fragment order (Gtl, coalesced 1KB/frag).
// ---------------------------------------------------------------------------
__global__ __launch_bounds__(256) void out_gemm(
    const float* __restrict__ H,              // [16384][512]
    const unsigned short* __restrict__ Gtl,   // tiled G, diag folded
    float* __restrict__ Out)
{
    const int r0 = blockIdx.x * 64;
    const int tid = threadIdx.x;
    const int wave = tid >> 6, lane = tid & 63;
    const int lrow = lane & 15, q = lane >> 4;

    __shared__ unsigned short hlds[64 * D_DIM];  // 64 KiB, swizzled
    char* lds = (char*)hlds;

    // stage H: wave w rows [16w, 16w+16); lane covers cols [8*lane, +8)
#pragma unroll
    for (int i = 0; i < 16; ++i) {
        const int row = wave * 16 + i;
        const float* src = H + (size_t)(r0 + row) * D_DIM + lane * 8;
        const float4 v0 = *(const float4*)src;
        const float4 v1 = *(const float4*)(src + 4);
        short8 pk;
        pk[0] = (short)f32_to_bf16(v0.x); pk[1] = (short)f32_to_bf16(v0.y);
        pk[2] = (short)f32_to_bf16(v0.z); pk[3] = (short)f32_to_bf16(v0.w);
        pk[4] = (short)f32_to_bf16(v1.x); pk[5] = (short)f32_to_bf16(v1.y);
        pk[6] = (short)f32_to_bf16(v1.z); pk[7] = (short)f32_to_bf16(v1.w);
        int byte = row * 1024 + lane * 16;
        byte ^= (row & 7) << 4;
        *(short8*)(lds + byte) = pk;
    }
    __syncthreads();

    // this wave's G tiles: e-groups [wave*8, wave*8+8), all 16 k-tiles
    const char* gtb = (const char*)Gtl + ((size_t)(wave * 8 * 16) << 10)
                      + ((size_t)lane << 4);

    floatx4 acc[4][8] = {};
#pragma unroll
    for (int kk = 0; kk < 16; ++kk) {
        short8 a[4];
#pragma unroll
        for (int m = 0; m < 4; ++m) {
            const int row = m * 16 + lrow;
            int byte = row * 1024 + kk * 64 + q * 16;
            byte ^= (row & 7) << 4;
            a[m] = *(const short8*)(lds + byte);
        }
#pragma unroll
        for (int nh = 0; nh < 2; ++nh) {
            short8 b[4];
#pragma unroll
            for (int n = 0; n < 4; ++n)
                b[n] = *(const short8*)(gtb + ((size_t)((nh * 4 + n) * 16 + kk) << 10));
#pragma unroll
            for (int n = 0; n < 4; ++n)
#pragma unroll
                for (int m = 0; m < 4; ++m)
                    acc[m][nh * 4 + n] = __builtin_amdgcn_mfma_f32_16x16x32_bf16(
                        a[m], b[n], acc[m][nh * 4 + n], 0, 0, 0);
        }
    }

    // epilogue: Out[r][e] = acc (diag already in G)
#pragma unroll
    for (int m = 0; m < 4; ++m) {
#pragma unroll
        for (int j = 0; j < 4; ++j) {
            const int r = r0 + m * 16 + q * 4 + j;
#pragma unroll
            for (int n = 0; n < 8; ++n) {
                const int e = wave * 128 + n * 16 + lrow;
                Out[(size_t)r * D_DIM + e] = acc[m][n][j];
            }
        }
    }
}

// ---------------------------------------------------------------------------
extern "C" void kernel_launch(void* const* d_in, const int* in_sizes, int n_in,
                              void* d_out, int out_size, void* d_ws, size_t ws_size,
                              hipStream_t stream)
{
    const float* H    = (const float*)d_in[0];   // (4,4096,512)
    const float* W    = (const float*)d_in[1];   // (512,512)
    const float* gate = (const float*)d_in[2];   // (1,)
    const float* prec = (const float*)d_in[3];   // (512,)
    float* out = (float*)d_out;
    char* ws = (char*)d_ws;

    unsigned short* Ltl = (unsigned short*)(ws);                 // 512 KiB (tiled)
    unsigned short* Gtl = (unsigned short*)(ws + (512u << 10));  // 512 KiB (tiled)

    prep_kernel<<<dim3(D_DIM), dim3(64), 0, stream>>>(W, Ltl);

    chain_kernel<<<dim3(D_DIM / 16), dim3(256), 0, stream>>>(
        Ltl, prec, gate, Gtl);

    out_gemm<<<dim3(16384 / 64), dim3(256), 0, stream>>>(H, Gtl, out);
}

// Round 16
// 110.118 us; speedup vs baseline: 1.3161x; 1.3161x over previous
//
#include <hip/hip_runtime.h>
#include <stdint.h>

#define D_DIM 512
#define NSTEPS 10
#define ALPHA0 0.1f
#define DT_C 0.1f
#define BETA_C 2.8982753492378875f

typedef __attribute__((ext_vector_type(8))) short short8;
typedef __attribute__((ext_vector_type(4))) float floatx4;
typedef __attribute__((ext_vector_type(4))) unsigned short ushortx4;
typedef unsigned int u32;

__device__ __forceinline__ unsigned short f32_to_bf16(float f) {
    union { float f; uint32_t u; } v;
    v.f = f;
    uint32_t u = v.u;
    return (unsigned short)((u + 0x7FFFu + ((u >> 16) & 1u)) >> 16);
}

__device__ __forceinline__ void async_load16(u32* lds, const u32* g) {
    __builtin_amdgcn_global_load_lds((const __attribute__((address_space(1))) u32*)g,
                                     (__attribute__((address_space(3))) u32*)lds, 16, 0, 0);
}

// ---------------------------------------------------------------------------
// Kernel 1: build L_rw and store PRE-TILED in MFMA fragment order (round 13).
// Tile (eg32, kk) stored as two 1KB halves; byte l*16 of a half is exactly
// the fragment MFMA-lane l consumes.
// ---------------------------------------------------------------------------
__global__ __launch_bounds__(64) void prep_kernel(
    const float* __restrict__ W,
    unsigned short* __restrict__ Ltl)    // 512 KiB, tiled layout
{
    const int e = blockIdx.x;
    const int lane = threadIdx.x;
    const float* w = W + (size_t)e * D_DIM + lane * 8;
    const float4 v0 = *(const float4*)w;
    const float4 v1 = *(const float4*)(w + 4);
    float a[8] = { fabsf(v0.x), fabsf(v0.y), fabsf(v0.z), fabsf(v0.w),
                   fabsf(v1.x), fabsf(v1.y), fabsf(v1.z), fabsf(v1.w) };
    float s = a[0] + a[1] + a[2] + a[3] + a[4] + a[5] + a[6] + a[7];
#pragma unroll
    for (int off = 1; off < 64; off <<= 1) s += __shfl_xor(s, off, 64);
    const float inv = 1.0f / fmaxf(s, 1e-8f);
    short8 pk;
#pragma unroll
    for (int j = 0; j < 8; ++j) {
        const float diag = ((lane * 8 + j) == e) ? 1.0f : 0.0f;
        pk[j] = (short)f32_to_bf16(diag - a[j] * inv);
    }
    const int eg = e >> 5, half = (e >> 4) & 1, r = e & 15;
    const int kk = lane >> 2, qp = lane & 3;
    char* dst = (char*)Ltl + ((size_t)(eg * 32 + kk * 2 + half) << 10)
                + ((size_t)(qp * 16 + r) << 4);
    *(short8*)dst = pk;
}

// ---------------------------------------------------------------------------
// Kernel 2: full 10-step settle, ONE launch, 32 blocks x 1024 thr.
// EXACT round-14 structure (measured 77.4us, best chain):
//   16 waves; wave w owns e-rows [32w, 32w+32) (2 m-frags).
//   L streamed L2->LDS via global_load_lds from the tiled layout: per kk,
//   2 x 1KB fully-contiguous loads, 4-slot wave-private ring, depth-3 lead,
//   counted s_waitcnt vmcnt(6) (never 0 in-loop).
//   Abuf (A bf16 [c][d] swizzled, 16 KB) single-buffered; per-step barriers
//   raw lgkmcnt(0)+s_barrier (LDS-only) so the async ring survives them.
// Epilogue: Gtl = g*A10 + (1-g)I PRE-TILED (fragment order), eg16 = wave*2+m.
// ---------------------------------------------------------------------------
__global__ __launch_bounds__(1024) void chain_kernel(
    const unsigned short* __restrict__ Ltl,   // tiled L (see prep)
    const float* __restrict__ prec,
    const float* __restrict__ gate_alpha,
    unsigned short* __restrict__ Gtl)         // tiled G, diag folded
{
    const int tid = threadIdx.x;
    const int wave = tid >> 6, lane = tid & 63;
    const int lrow = lane & 15, q = lane >> 4;
    const int c_glob = blockIdx.x * 16 + lrow;
    const int ebase = wave * 32;

    __shared__ unsigned short Abuf[16 * D_DIM];    // 16 KiB, swizzled [c][d]
    __shared__ unsigned short Lt[4][16][1024];     // 128 KiB: [slot][wave][2KB tile]
    char* abuf = (char*)Abuf;

    // this wave's tile run: tiles (wave, kk) at base + kk*2048, halves +0/+1024
    const char* gbase = (const char*)Ltl + ((size_t)wave << 15) + ((size_t)lane << 4);

    // prec hoisted: pr = precision[e] for this lane's 8 e's
    float pr[2][4];
#pragma unroll
    for (int m = 0; m < 2; ++m)
#pragma unroll
        for (int j = 0; j < 4; ++j)
            pr[m][j] = prec[ebase + m * 16 + q * 4 + j];

    floatx4 At[2], Bt[2];
#pragma unroll
    for (int m = 0; m < 2; ++m) {
#pragma unroll
        for (int j = 0; j < 4; ++j) {
            const int e = ebase + m * 16 + q * 4 + j;
            At[m][j] = (e == c_glob) ? 1.0f : 0.0f;
            Bt[m][j] = 0.0f;
        }
    }

    // init Abuf with A0 = I
#pragma unroll
    for (int m = 0; m < 2; ++m) {
        ushortx4 pk;
#pragma unroll
        for (int j = 0; j < 4; ++j) pk[j] = f32_to_bf16(At[m][j]);
        int byte = lrow * (D_DIM * 2) + (ebase + m * 16 + q * 4) * 2;
        byte ^= (lrow & 7) << 4;
        *(ushortx4*)(abuf + byte) = pk;
    }
    __syncthreads();

    // prime ring: tiles 0,1,2 into slots 0,1,2 (6 loads in flight)
#pragma unroll
    for (int t = 0; t < 3; ++t) {
        char* dst = (char*)&Lt[t][wave][0];
        async_load16((u32*)dst, (const u32*)(gbase + t * 2048));
        async_load16((u32*)(dst + 1024), (const u32*)(gbase + t * 2048 + 1024));
    }

    for (int step = 0; step < NSTEPS; ++step) {
        floatx4 acc[2] = {};
#pragma unroll
        for (int kk = 0; kk < 16; ++kk) {
            // prefetch tile kk+3 into slot (kk+3)&3
            {
                const int kp = (kk + 3) & 15;
                char* dst = (char*)&Lt[(kk + 3) & 3][wave][0];
                async_load16((u32*)dst, (const u32*)(gbase + kp * 2048));
                async_load16((u32*)(dst + 1024), (const u32*)(gbase + kp * 2048 + 1024));
            }
            // tile kk's 2 loads are the oldest of <=8 outstanding
            asm volatile("s_waitcnt vmcnt(6)" ::: "memory");
            __builtin_amdgcn_sched_barrier(0);

            const char* lt = (const char*)&Lt[kk & 3][wave][0];
            const short8 a0 = *(const short8*)(lt + lane * 16);
            const short8 a1 = *(const short8*)(lt + 1024 + lane * 16);

            int bbyte = lrow * (D_DIM * 2) + (kk * 32 + q * 8) * 2;
            bbyte ^= (lrow & 7) << 4;
            const short8 b = *(const short8*)(abuf + bbyte);

            acc[0] = __builtin_amdgcn_mfma_f32_16x16x32_bf16(a0, b, acc[0], 0, 0, 0);
            acc[1] = __builtin_amdgcn_mfma_f32_16x16x32_bf16(a1, b, acc[1], 0, 0, 0);
        }

#pragma unroll
        for (int m = 0; m < 2; ++m) {
#pragma unroll
            for (int j = 0; j < 4; ++j) {
                const int e = ebase + m * 16 + q * 4 + j;
                const float p = pr[m][j];
                const float tgt = (e == c_glob) ? p : 0.0f;
                const float force = -acc[m][j] - (ALPHA0 + p) * At[m][j]
                                    + tgt - BETA_C * Bt[m][j];
                Bt[m][j] += DT_C * force;
                At[m][j] += DT_C * Bt[m][j];
            }
        }

        if (step < NSTEPS - 1) {
            // all waves done reading Abuf (LDS ordering only; vmcnt untouched
            // so the async L ring stays in flight across the barrier)
            asm volatile("s_waitcnt lgkmcnt(0)\n\ts_barrier" ::: "memory");
            __builtin_amdgcn_sched_barrier(0);
#pragma unroll
            for (int m = 0; m < 2; ++m) {
                ushortx4 pk;
#pragma unroll
                for (int j = 0; j < 4; ++j) pk[j] = f32_to_bf16(At[m][j]);
                int byte = lrow * (D_DIM * 2) + (ebase + m * 16 + q * 4) * 2;
                byte ^= (lrow & 7) << 4;
                *(ushortx4*)(abuf + byte) = pk;
            }
            asm volatile("s_waitcnt lgkmcnt(0)\n\ts_barrier" ::: "memory");
            __builtin_amdgcn_sched_barrier(0);
        }
    }

    // epilogue: G = g*A10 + (1-g)I, written PRE-TILED (fragment order).
    // E = ebase+m*16+q*4+j -> eg16 = wave*2+m; D = c_glob, kt = c_glob>>5.
    const float g = tanhf(gate_alpha[0]);
    const int kt = c_glob >> 5;
    const int lq = ((c_glob >> 3) & 3) * 16;
    const int jb = (c_glob & 7) * 2;
#pragma unroll
    for (int m = 0; m < 2; ++m) {
        char* tbase = (char*)Gtl + ((size_t)((wave * 2 + m) * 16 + kt) << 10);
#pragma unroll
        for (int j = 0; j < 4; ++j) {
            const int e = ebase + m * 16 + q * 4 + j;
            float val = g * At[m][j];
            if (e == c_glob) val += (1.0f - g);
            *(unsigned short*)(tbase + (q * 4 + j + lq) * 16 + jb) = f32_to_bf16(val);
        }
    }
}

// ---------------------------------------------------------------------------
// Kernel 3: out = Hbf @ G^T (diag folded into G).
// EXACT round-15 structure (measured ~22us, best out_gemm):
//   64-row tiles, 256 blocks x 256 thr (4 waves); halves G re-read vs 32-row.
//   H staged in 64 KB swizzled LDS; G consumed directly from L2 in fragment
//   order (Gtl, 1KB coalesced per frag). acc[4][8] + a[4] + b[4] ~= 210 regs.
// ---------------------------------------------------------------------------
__global__ __launch_bounds__(256) void out_gemm(
    const float* __restrict__ H,              // [16384][512]
    const unsigned short* __restrict__ Gtl,   // tiled G, diag folded
    float* __restrict__ Out)
{
    const int r0 = blockIdx.x * 64;
    const int tid = threadIdx.x;
    const int wave = tid >> 6, lane = tid & 63;
    const int lrow = lane & 15, q = lane >> 4;

    __shared__ unsigned short hlds[64 * D_DIM];  // 64 KiB, swizzled
    char* lds = (char*)hlds;

    // stage H: wave w rows [16w, 16w+16); lane covers cols [8*lane, +8)
#pragma unroll
    for (int i = 0; i < 16; ++i) {
        const int row = wave * 16 + i;
        const float* src = H + (size_t)(r0 + row) * D_DIM + lane * 8;
        const float4 v0 = *(const float4*)src;
        const float4 v1 = *(const float4*)(src + 4);
        short8 pk;
        pk[0] = (short)f32_to_bf16(v0.x); pk[1] = (short)f32_to_bf16(v0.y);
        pk[2] = (short)f32_to_bf16(v0.z); pk[3] = (short)f32_to_bf16(v0.w);
        pk[4] = (short)f32_to_bf16(v1.x); pk[5] = (short)f32_to_bf16(v1.y);
        pk[6] = (short)f32_to_bf16(v1.z); pk[7] = (short)f32_to_bf16(v1.w);
        int byte = row * 1024 + lane * 16;
        byte ^= (row & 7) << 4;
        *(short8*)(lds + byte) = pk;
    }
    __syncthreads();

    // this wave's G tiles: e-groups [wave*8, wave*8+8), all 16 k-tiles
    const char* gtb = (const char*)Gtl + ((size_t)(wave * 8 * 16) << 10)
                      + ((size_t)lane << 4);

    floatx4 acc[4][8] = {};
#pragma unroll
    for (int kk = 0; kk < 16; ++kk) {
        short8 a[4];
#pragma unroll
        for (int m = 0; m < 4; ++m) {
            const int row = m * 16 + lrow;
            int byte = row * 1024 + kk * 64 + q * 16;
            byte ^= (row & 7) << 4;
            a[m] = *(const short8*)(lds + byte);
        }
#pragma unroll
        for (int nh = 0; nh < 2; ++nh) {
            short8 b[4];
#pragma unroll
            for (int n = 0; n < 4; ++n)
                b[n] = *(const short8*)(gtb + ((size_t)((nh * 4 + n) * 16 + kk) << 10));
#pragma unroll
            for (int n = 0; n < 4; ++n)
#pragma unroll
                for (int m = 0; m < 4; ++m)
                    acc[m][nh * 4 + n] = __builtin_amdgcn_mfma_f32_16x16x32_bf16(
                        a[m], b[n], acc[m][nh * 4 + n], 0, 0, 0);
        }
    }

    // epilogue: Out[r][e] = acc (diag already in G)
#pragma unroll
    for (int m = 0; m < 4; ++m) {
#pragma unroll
        for (int j = 0; j < 4; ++j) {
            const int r = r0 + m * 16 + q * 4 + j;
#pragma unroll
            for (int n = 0; n < 8; ++n) {
                const int e = wave * 128 + n * 16 + lrow;
                Out[(size_t)r * D_DIM + e] = acc[m][n][j];
            }
        }
    }
}

// ---------------------------------------------------------------------------
extern "C" void kernel_launch(void* const* d_in, const int* in_sizes, int n_in,
                              void* d_out, int out_size, void* d_ws, size_t ws_size,
                              hipStream_t stream)
{
    const float* H    = (const float*)d_in[0];   // (4,4096,512)
    const float* W    = (const float*)d_in[1];   // (512,512)
    const float* gate = (const float*)d_in[2];   // (1,)
    const float* prec = (const float*)d_in[3];   // (512,)
    float* out = (float*)d_out;
    char* ws = (char*)d_ws;

    unsigned short* Ltl = (unsigned short*)(ws);                 // 512 KiB (tiled)
    unsigned short* Gtl = (unsigned short*)(ws + (512u << 10));  // 512 KiB (tiled)

    prep_kernel<<<dim3(D_DIM), dim3(64), 0, stream>>>(W, Ltl);

    chain_kernel<<<dim3(D_DIM / 16), dim3(1024), 0, stream>>>(
        Ltl, prec, gate, Gtl);

    out_gemm<<<dim3(16384 / 64), dim3(256), 0, stream>>>(H, Gtl, out);
}